// Round 5
// baseline (1128.115 us; speedup 1.0000x reference)
//
#include <hip/hip_runtime.h>

// residualBlock: two sparse 3x3x3 convs (gather-GEMM over 27 offsets), ReLU
// between, residual add. bf16 MFMA.
//
// R5: convs are VMEM *address-issue* bound (~1 addr/cyc/CU fits R1/R3 at
// ~137us regardless of occupancy). 84% of A-gather addresses hit the
// sentinel zero row -> exec-mask them away: zero A frags, load only valid
// lanes (masked lanes issue no addresses). Plus: CHUNK=6 (48KB LDS, 3
// blocks/CU) with launch_bounds(256,3) so VGPRs (cap 168) do NOT spill
// (R4's bounds(256,4) spilled 600MB/conv of scratch -> regression).
//
// ws layout (~95.9 MB):
//   xb  : bf16 x, (N+1) x 64   (row N = zeros, sentinel)      33,554,560 B
//   yb  : bf16 relu(conv1), (N+1) x 64 (row N = zeros)        33,554,560 B
//   Wta : bf16 Wa^T [k][j][i]                                    221,184 B
//   Wtb : bf16 Wb^T [k][j][i]                                    221,184 B
//   nbrT: int  [27][N]                                        28,311,552 B

#define N_ROWS 262144
#define HCH    64
#define KOFF   27
#define CHUNK  6
#define NCHUNK 5           // chunks: 6,6,6,6,3

typedef unsigned short u16;
typedef __attribute__((ext_vector_type(8))) short short8;   // 8 bf16 (4 VGPRs)
typedef __attribute__((ext_vector_type(4))) float f32x4;    // 4 fp32 acc

__device__ __forceinline__ u16 f2bf(float f) {
    unsigned u = __builtin_bit_cast(unsigned, f);
    unsigned r = (u + 0x7FFFu + ((u >> 16) & 1u)) >> 16;   // RNE
    return (u16)r;
}
__device__ __forceinline__ float bf2f(u16 h) {
    return __builtin_bit_cast(float, (unsigned)h << 16);
}
__device__ __forceinline__ unsigned pack2(float a, float b) {
    return (unsigned)f2bf(a) | ((unsigned)f2bf(b) << 16);
}

// ------------------------------------------------------------------ prep ----
// One fused dispatch: [0,8193) prep_x ; [8193,9057) prep_w ; [9057,17249) nbrT
__global__ void prep_all(const float* __restrict__ x, u16* __restrict__ xb,
                         u16* __restrict__ yb,
                         const float* __restrict__ Wa, const float* __restrict__ Wb,
                         u16* __restrict__ Wta, u16* __restrict__ Wtb,
                         const int* __restrict__ nbr, int* __restrict__ nbrT) {
    const int b = blockIdx.x;
    if (b < 8193) {
        long gid = (long)b * 256 + threadIdx.x;             // 8-elem chunks
        const long total = (long)N_ROWS * HCH / 8;          // 2,097,152
        if (gid < total) {
            const float4* s = (const float4*)(x + gid * 8);
            float4 a = s[0], c = s[1];
            uint4 v;
            v.x = pack2(a.x, a.y); v.y = pack2(a.z, a.w);
            v.z = pack2(c.x, c.y); v.w = pack2(c.z, c.w);
            *(uint4*)(xb + gid * 8) = v;
        } else if (gid < total + HCH / 8) {                 // zero row N
            long c = gid - total;
            uint4 z; z.x = 0; z.y = 0; z.z = 0; z.w = 0;
            *(uint4*)(xb + (long)N_ROWS * HCH + c * 8) = z;
            *(uint4*)(yb + (long)N_ROWS * HCH + c * 8) = z;
        }
    } else if (b < 9057) {
        int gid = (b - 8193) * 256 + threadIdx.x;
        const int total = KOFF * HCH * HCH;                 // 110592
        const float* src; u16* dst; int e;
        if (gid < total)          { src = Wa; dst = Wta; e = gid; }
        else if (gid < 2 * total) { src = Wb; dst = Wtb; e = gid - total; }
        else return;
        int k = e >> 12, i = (e >> 6) & 63, j = e & 63;
        dst[(k << 12) + (j << 6) + i] = f2bf(src[e]);
    } else {
        __shared__ int t[32 * 27];
        const int rowbase = (b - 9057) * 32;
        for (int e = threadIdx.x; e < 32 * 27; e += 256)
            t[e] = nbr[(size_t)rowbase * KOFF + e];
        __syncthreads();
        for (int e = threadIdx.x; e < 32 * 27; e += 256) {
            int k = e >> 5, r = e & 31;
            nbrT[(size_t)k * N_ROWS + rowbase + r] = t[r * KOFF + k];
        }
    }
}

// ------------------------------------------------------------------ conv ----
template <bool FIRST>
__global__ __launch_bounds__(256, 3) void conv_kernel(
    const u16* __restrict__ xg,      // gathered-from features, (N+1) x 64 bf16
    const u16* __restrict__ Wt,      // [27][64][64] bf16, [k][j][i]
    const int* __restrict__ nb,      // nbrT[27][N]
    u16* __restrict__ ybf,           // FIRST: relu output bf16
    float* __restrict__ outf,        // !FIRST: final fp32 output
    const u16* __restrict__ residb)  // !FIRST: residual x (bf16)
{
    __shared__ uint4 Wlds4[CHUNK * 512];                    // 49,152 B
    u16*   Wsh = (u16*)Wlds4;
    float* Fsh = (float*)Wlds4;

    const int tid  = threadIdx.x;
    const int wave = tid >> 6;
    const int lane = tid & 63;
    const int m    = lane & 15;      // A row / B col / C col
    const int q    = lane >> 4;      // K-subgroup
    const int base = blockIdx.x * 256 + wave * 64;

    int row[4];
#pragma unroll
    for (int t = 0; t < 4; t++) row[t] = base + t * 16 + m;

    auto ld_idx = [&](int k, int t) -> int {
        return nb[(size_t)k * N_ROWS + row[t]];
    };

    // masked gather: sentinel lanes issue NO address (exec-masked off)
    auto ldA = [&](int idx, short8& a0, short8& a1) {
        short8 z = {0, 0, 0, 0, 0, 0, 0, 0};
        a0 = z; a1 = z;
        if (idx != N_ROWS) {
            const u16* ar = xg + (size_t)idx * HCH + q * 8;
            a0 = *(const short8*)ar;
            a1 = *(const short8*)(ar + 32);
        }
    };

    f32x4 acc[4][4];
#pragma unroll
    for (int t = 0; t < 4; t++)
#pragma unroll
        for (int jt = 0; jt < 4; jt++)
            acc[t][jt] = (f32x4){0.f, 0.f, 0.f, 0.f};

    // ---- pipeline prologue: idx(0..3), A(0), A(1) in flight ----
    int i0[4], i1[4], idxRing[2][4];
#pragma unroll
    for (int t = 0; t < 4; t++) i0[t] = ld_idx(0, t);
#pragma unroll
    for (int t = 0; t < 4; t++) i1[t] = ld_idx(1, t);
#pragma unroll
    for (int t = 0; t < 4; t++) idxRing[0][t] = ld_idx(2, t);
#pragma unroll
    for (int t = 0; t < 4; t++) idxRing[1][t] = ld_idx(3, t);

    short8 Aring[3][4][2];
#pragma unroll
    for (int t = 0; t < 4; t++) ldA(i0[t], Aring[0][t][0], Aring[0][t][1]);
#pragma unroll
    for (int t = 0; t < 4; t++) ldA(i1[t], Aring[1][t][0], Aring[1][t][1]);

#pragma unroll
    for (int c = 0; c < NCHUNK; c++) {
        const int SL = (c * CHUNK + CHUNK <= KOFF) ? CHUNK : (KOFF - c * CHUNK);
        // ---- stage W chunk into swizzled LDS ----
        __syncthreads();
        const uint4* wg = (const uint4*)(Wt + c * CHUNK * 4096);
#pragma unroll
        for (int e = tid; e < SL * 512; e += 256) {
            uint4 v = wg[e];
            int s = e >> 9, rem = e & 511, j = rem >> 3, cc = rem & 7;
            Wlds4[s * 512 + j * 8 + (cc ^ (j & 7))] = v;
        }
        __syncthreads();

#pragma unroll
        for (int s = 0; s < CHUNK; s++) {
            if (c * CHUNK + s >= KOFF) break;               // compile-time folded
            const int kk  = c * CHUNK + s;
            const int par = kk & 1;
            const int cur = kk % 3;
            const int nxt = (kk + 2) % 3;

            // issue A(kk+2) (indices arrived 2 iters ago), masked by validity
#pragma unroll
            for (int t = 0; t < 4; t++)
                ldA(idxRing[par][t], Aring[nxt][t][0], Aring[nxt][t][1]);
            // issue idx(kk+4)
            const int k4 = (kk + 4 < KOFF) ? kk + 4 : KOFF - 1;
#pragma unroll
            for (int t = 0; t < 4; t++) idxRing[par][t] = ld_idx(k4, t);

            // B frags from swizzled LDS (conflict-free b128)
            const u16* bs = Wsh + s * 4096;
            short8 B0[4], B1[4];
#pragma unroll
            for (int jt = 0; jt < 4; jt++) {
                int j = jt * 16 + m;
                B0[jt] = *(const short8*)(bs + j * 64 + ((q    ) ^ (m & 7)) * 8);
                B1[jt] = *(const short8*)(bs + j * 64 + ((q + 4) ^ (m & 7)) * 8);
            }

            // 32 MFMAs: all h0 (independent), then all h1
#pragma unroll
            for (int t = 0; t < 4; t++)
#pragma unroll
                for (int jt = 0; jt < 4; jt++)
                    acc[t][jt] = __builtin_amdgcn_mfma_f32_16x16x32_bf16(
                        Aring[cur][t][0], B0[jt], acc[t][jt], 0, 0, 0);
#pragma unroll
            for (int t = 0; t < 4; t++)
#pragma unroll
                for (int jt = 0; jt < 4; jt++)
                    acc[t][jt] = __builtin_amdgcn_mfma_f32_16x16x32_bf16(
                        Aring[cur][t][1], B1[jt], acc[t][jt], 0, 0, 0);
        }
    }

    // ---- epilogue: transpose through LDS, store full 128B lines ----
    float* sl = Fsh + wave * (16 * 68);                     // 4,352 B/wave
    const int r = lane & 15;                                // local row
    const int h = lane >> 4;                                // 16-col segment
#pragma unroll
    for (int t = 0; t < 4; t++) {
        __syncthreads();
#pragma unroll
        for (int jt = 0; jt < 4; jt++)
#pragma unroll
            for (int rr = 0; rr < 4; rr++)
                sl[(q * 4 + rr) * 68 + jt * 16 + m] = acc[t][jt][rr];
        __syncthreads();

        float4 v0 = *(const float4*)&sl[r * 68 + h * 16 + 0];
        float4 v1 = *(const float4*)&sl[r * 68 + h * 16 + 4];
        float4 v2 = *(const float4*)&sl[r * 68 + h * 16 + 8];
        float4 v3 = *(const float4*)&sl[r * 68 + h * 16 + 12];
        const size_t grow = (size_t)(base + t * 16 + r);
        if (FIRST) {
            uint4 o0, o1;
            o0.x = pack2(fmaxf(v0.x, 0.f), fmaxf(v0.y, 0.f));
            o0.y = pack2(fmaxf(v0.z, 0.f), fmaxf(v0.w, 0.f));
            o0.z = pack2(fmaxf(v1.x, 0.f), fmaxf(v1.y, 0.f));
            o0.w = pack2(fmaxf(v1.z, 0.f), fmaxf(v1.w, 0.f));
            o1.x = pack2(fmaxf(v2.x, 0.f), fmaxf(v2.y, 0.f));
            o1.y = pack2(fmaxf(v2.z, 0.f), fmaxf(v2.w, 0.f));
            o1.z = pack2(fmaxf(v3.x, 0.f), fmaxf(v3.y, 0.f));
            o1.w = pack2(fmaxf(v3.z, 0.f), fmaxf(v3.w, 0.f));
            uint4* dst = (uint4*)(ybf + grow * HCH + h * 16);
            dst[0] = o0; dst[1] = o1;
        } else {
            const uint4* rb = (const uint4*)(residb + grow * HCH + h * 16);
            uint4 r0 = rb[0], r1 = rb[1];
            float4 o;
            float* op = outf + grow * HCH + h * 16;
            o.x = v0.x + bf2f((u16)(r0.x & 0xFFFF));
            o.y = v0.y + bf2f((u16)(r0.x >> 16));
            o.z = v0.z + bf2f((u16)(r0.y & 0xFFFF));
            o.w = v0.w + bf2f((u16)(r0.y >> 16));
            *(float4*)(op + 0) = o;
            o.x = v1.x + bf2f((u16)(r0.z & 0xFFFF));
            o.y = v1.y + bf2f((u16)(r0.z >> 16));
            o.z = v1.z + bf2f((u16)(r0.w & 0xFFFF));
            o.w = v1.w + bf2f((u16)(r0.w >> 16));
            *(float4*)(op + 4) = o;
            o.x = v2.x + bf2f((u16)(r1.x & 0xFFFF));
            o.y = v2.y + bf2f((u16)(r1.x >> 16));
            o.z = v2.z + bf2f((u16)(r1.y & 0xFFFF));
            o.w = v2.w + bf2f((u16)(r1.y >> 16));
            *(float4*)(op + 8) = o;
            o.x = v3.x + bf2f((u16)(r1.z & 0xFFFF));
            o.y = v3.y + bf2f((u16)(r1.z >> 16));
            o.z = v3.z + bf2f((u16)(r1.w & 0xFFFF));
            o.w = v3.w + bf2f((u16)(r1.w >> 16));
            *(float4*)(op + 12) = o;
        }
    }
}

// ---------------------------------------------------------------- launch ----
extern "C" void kernel_launch(void* const* d_in, const int* in_sizes, int n_in,
                              void* d_out, int out_size, void* d_ws, size_t ws_size,
                              hipStream_t stream) {
    const float* x   = (const float*)d_in[0];
    const float* Wa  = (const float*)d_in[1];
    const float* Wb  = (const float*)d_in[2];
    const int*   nbr = (const int*)d_in[3];
    float* out = (float*)d_out;

    char* ws = (char*)d_ws;
    const size_t xb_bytes = (size_t)(N_ROWS + 1) * HCH * sizeof(u16); // 33,554,560
    const size_t w_bytes  = (size_t)KOFF * HCH * HCH * sizeof(u16);   //    221,184
    u16* xb  = (u16*)ws;
    u16* yb  = (u16*)(ws + xb_bytes);
    u16* Wta = (u16*)(ws + 2 * xb_bytes);
    u16* Wtb = (u16*)(ws + 2 * xb_bytes + w_bytes);
    int* nbrT = (int*)(ws + 2 * xb_bytes + 2 * w_bytes);

    prep_all<<<17249, 256, 0, stream>>>(x, xb, yb, Wa, Wb, Wta, Wtb, nbr, nbrT);
    conv_kernel<true ><<<N_ROWS / 256, 256, 0, stream>>>(xb, Wta, nbrT, yb, nullptr, nullptr);
    conv_kernel<false><<<N_ROWS / 256, 256, 0, stream>>>(yb, Wtb, nbrT, nullptr, out, xb);
}

// Round 6
// 322.202 us; speedup vs baseline: 3.5013x; 3.5013x over previous
//
#include <hip/hip_runtime.h>

// residualBlock: two sparse 3x3x3 convs (gather-GEMM over 27 offsets), ReLU
// between, residual add. bf16 MFMA.
//
// R6 = R3 structure EXACTLY (CHUNK=9, 72KB LDS, launch_bounds(256,2): VGPR
// cap 256, known non-spilling at 116 arch VGPR) + exec-masked A-gathers:
// 84% of gather addresses hit the sentinel zero row; `if (idx != N)` masks
// those lanes off so they issue NO memory requests (TA address work -6x).
// R4/R5 both died to launch_bounds-induced scratch spills (FETCH/WRITE
// ballooned to 0.6-1.8 GB) -- do NOT tighten launch bounds on this kernel.
//
// ws layout (~95.9 MB):
//   xb  : bf16 x, (N+1) x 64   (row N = zeros, sentinel)      33,554,560 B
//   yb  : bf16 relu(conv1), (N+1) x 64 (row N = zeros)        33,554,560 B
//   Wta : bf16 Wa^T [k][j][i]                                    221,184 B
//   Wtb : bf16 Wb^T [k][j][i]                                    221,184 B
//   nbrT: int  [27][N]                                        28,311,552 B

#define N_ROWS 262144
#define HCH    64
#define KOFF   27
#define CHUNK  9

typedef unsigned short u16;
typedef __attribute__((ext_vector_type(8))) short short8;   // 8 bf16 (4 VGPRs)
typedef __attribute__((ext_vector_type(4))) float f32x4;    // 4 fp32 acc

__device__ __forceinline__ u16 f2bf(float f) {
    unsigned u = __builtin_bit_cast(unsigned, f);
    unsigned r = (u + 0x7FFFu + ((u >> 16) & 1u)) >> 16;   // RNE
    return (u16)r;
}
__device__ __forceinline__ float bf2f(u16 h) {
    return __builtin_bit_cast(float, (unsigned)h << 16);
}
__device__ __forceinline__ unsigned pack2(float a, float b) {
    return (unsigned)f2bf(a) | ((unsigned)f2bf(b) << 16);
}

// ------------------------------------------------------------------ prep ----
// One fused dispatch: [0,8193) prep_x ; [8193,9057) prep_w ; [9057,17249) nbrT
__global__ void prep_all(const float* __restrict__ x, u16* __restrict__ xb,
                         u16* __restrict__ yb,
                         const float* __restrict__ Wa, const float* __restrict__ Wb,
                         u16* __restrict__ Wta, u16* __restrict__ Wtb,
                         const int* __restrict__ nbr, int* __restrict__ nbrT) {
    const int b = blockIdx.x;
    if (b < 8193) {
        long gid = (long)b * 256 + threadIdx.x;             // 8-elem chunks
        const long total = (long)N_ROWS * HCH / 8;          // 2,097,152
        if (gid < total) {
            const float4* s = (const float4*)(x + gid * 8);
            float4 a = s[0], c = s[1];
            uint4 v;
            v.x = pack2(a.x, a.y); v.y = pack2(a.z, a.w);
            v.z = pack2(c.x, c.y); v.w = pack2(c.z, c.w);
            *(uint4*)(xb + gid * 8) = v;
        } else if (gid < total + HCH / 8) {                 // zero row N
            long c = gid - total;
            uint4 z; z.x = 0; z.y = 0; z.z = 0; z.w = 0;
            *(uint4*)(xb + (long)N_ROWS * HCH + c * 8) = z;
            *(uint4*)(yb + (long)N_ROWS * HCH + c * 8) = z;
        }
    } else if (b < 9057) {
        int gid = (b - 8193) * 256 + threadIdx.x;
        const int total = KOFF * HCH * HCH;                 // 110592
        const float* src; u16* dst; int e;
        if (gid < total)          { src = Wa; dst = Wta; e = gid; }
        else if (gid < 2 * total) { src = Wb; dst = Wtb; e = gid - total; }
        else return;
        int k = e >> 12, i = (e >> 6) & 63, j = e & 63;
        dst[(k << 12) + (j << 6) + i] = f2bf(src[e]);
    } else {
        __shared__ int t[32 * 27];
        const int rowbase = (b - 9057) * 32;
        for (int e = threadIdx.x; e < 32 * 27; e += 256)
            t[e] = nbr[(size_t)rowbase * KOFF + e];
        __syncthreads();
        for (int e = threadIdx.x; e < 32 * 27; e += 256) {
            int k = e >> 5, r = e & 31;
            nbrT[(size_t)k * N_ROWS + rowbase + r] = t[r * KOFF + k];
        }
    }
}

// ------------------------------------------------------------------ conv ----
template <bool FIRST>
__global__ __launch_bounds__(256, 2) void conv_kernel(
    const u16* __restrict__ xg,      // gathered-from features, (N+1) x 64 bf16
    const u16* __restrict__ Wt,      // [27][64][64] bf16, [k][j][i]
    const int* __restrict__ nb,      // nbrT[27][N]
    u16* __restrict__ ybf,           // FIRST: relu output bf16
    float* __restrict__ outf,        // !FIRST: final fp32 output
    const u16* __restrict__ residb)  // !FIRST: residual x (bf16)
{
    __shared__ uint4 Wlds4[CHUNK * 512];                    // 73,728 B
    u16*   Wsh = (u16*)Wlds4;
    float* Fsh = (float*)Wlds4;

    const int tid  = threadIdx.x;
    const int wave = tid >> 6;
    const int lane = tid & 63;
    const int m    = lane & 15;      // A row / B col / C col
    const int q    = lane >> 4;      // K-subgroup
    const int base = blockIdx.x * 256 + wave * 64;

    int row[4];
#pragma unroll
    for (int t = 0; t < 4; t++) row[t] = base + t * 16 + m;

    auto ld_idx = [&](int k, int t) -> int {
        return nb[(size_t)k * N_ROWS + row[t]];
    };

    // masked gather: sentinel lanes are exec-masked off -> no addresses issued
    auto ldA = [&](int idx, short8& a0, short8& a1) {
        short8 z = {0, 0, 0, 0, 0, 0, 0, 0};
        a0 = z; a1 = z;
        if (idx != N_ROWS) {
            const u16* ar = xg + (size_t)idx * HCH + q * 8;
            a0 = *(const short8*)ar;
            a1 = *(const short8*)(ar + 32);
        }
    };

    f32x4 acc[4][4];
#pragma unroll
    for (int t = 0; t < 4; t++)
#pragma unroll
        for (int jt = 0; jt < 4; jt++)
            acc[t][jt] = (f32x4){0.f, 0.f, 0.f, 0.f};

    // ---- pipeline prologue: idx(0..3), A(0), A(1) in flight ----
    int i0[4], i1[4], idxRing[2][4];
#pragma unroll
    for (int t = 0; t < 4; t++) i0[t] = ld_idx(0, t);
#pragma unroll
    for (int t = 0; t < 4; t++) i1[t] = ld_idx(1, t);
#pragma unroll
    for (int t = 0; t < 4; t++) idxRing[0][t] = ld_idx(2, t);
#pragma unroll
    for (int t = 0; t < 4; t++) idxRing[1][t] = ld_idx(3, t);

    short8 Aring[3][4][2];
#pragma unroll
    for (int t = 0; t < 4; t++) ldA(i0[t], Aring[0][t][0], Aring[0][t][1]);
#pragma unroll
    for (int t = 0; t < 4; t++) ldA(i1[t], Aring[1][t][0], Aring[1][t][1]);

#pragma unroll
    for (int c = 0; c < KOFF / CHUNK; c++) {
        // ---- stage W chunk into swizzled LDS ----
        __syncthreads();
        const uint4* wg = (const uint4*)(Wt + c * CHUNK * 4096);
#pragma unroll
        for (int e = tid; e < CHUNK * 512; e += 256) {
            uint4 v = wg[e];
            int s = e >> 9, rem = e & 511, j = rem >> 3, cc = rem & 7;
            Wlds4[s * 512 + j * 8 + (cc ^ (j & 7))] = v;
        }
        __syncthreads();

#pragma unroll
        for (int s = 0; s < CHUNK; s++) {
            const int kk  = c * CHUNK + s;
            const int par = kk & 1;
            const int cur = kk % 3;
            const int nxt = (kk + 2) % 3;

            // issue A(kk+2) (indices arrived 2 iters ago), exec-masked
#pragma unroll
            for (int t = 0; t < 4; t++)
                ldA(idxRing[par][t], Aring[nxt][t][0], Aring[nxt][t][1]);
            // issue idx(kk+4)
            const int k4 = (kk + 4 < KOFF) ? kk + 4 : KOFF - 1;
#pragma unroll
            for (int t = 0; t < 4; t++) idxRing[par][t] = ld_idx(k4, t);

            // B frags from swizzled LDS (conflict-free b128)
            const u16* bs = Wsh + s * 4096;
            short8 B0[4], B1[4];
#pragma unroll
            for (int jt = 0; jt < 4; jt++) {
                int j = jt * 16 + m;
                B0[jt] = *(const short8*)(bs + j * 64 + ((q    ) ^ (m & 7)) * 8);
                B1[jt] = *(const short8*)(bs + j * 64 + ((q + 4) ^ (m & 7)) * 8);
            }

            // 32 MFMAs: all h0 (independent), then all h1
#pragma unroll
            for (int t = 0; t < 4; t++)
#pragma unroll
                for (int jt = 0; jt < 4; jt++)
                    acc[t][jt] = __builtin_amdgcn_mfma_f32_16x16x32_bf16(
                        Aring[cur][t][0], B0[jt], acc[t][jt], 0, 0, 0);
#pragma unroll
            for (int t = 0; t < 4; t++)
#pragma unroll
                for (int jt = 0; jt < 4; jt++)
                    acc[t][jt] = __builtin_amdgcn_mfma_f32_16x16x32_bf16(
                        Aring[cur][t][1], B1[jt], acc[t][jt], 0, 0, 0);
        }
    }

    // ---- epilogue: transpose through LDS, store full 128B lines ----
    float* sl = Fsh + wave * (16 * 68);                     // 4,352 B/wave
    const int r = lane & 15;                                // local row
    const int h = lane >> 4;                                // 16-col segment
#pragma unroll
    for (int t = 0; t < 4; t++) {
        __syncthreads();
#pragma unroll
        for (int jt = 0; jt < 4; jt++)
#pragma unroll
            for (int rr = 0; rr < 4; rr++)
                sl[(q * 4 + rr) * 68 + jt * 16 + m] = acc[t][jt][rr];
        __syncthreads();

        float4 v0 = *(const float4*)&sl[r * 68 + h * 16 + 0];
        float4 v1 = *(const float4*)&sl[r * 68 + h * 16 + 4];
        float4 v2 = *(const float4*)&sl[r * 68 + h * 16 + 8];
        float4 v3 = *(const float4*)&sl[r * 68 + h * 16 + 12];
        const size_t grow = (size_t)(base + t * 16 + r);
        if (FIRST) {
            uint4 o0, o1;
            o0.x = pack2(fmaxf(v0.x, 0.f), fmaxf(v0.y, 0.f));
            o0.y = pack2(fmaxf(v0.z, 0.f), fmaxf(v0.w, 0.f));
            o0.z = pack2(fmaxf(v1.x, 0.f), fmaxf(v1.y, 0.f));
            o0.w = pack2(fmaxf(v1.z, 0.f), fmaxf(v1.w, 0.f));
            o1.x = pack2(fmaxf(v2.x, 0.f), fmaxf(v2.y, 0.f));
            o1.y = pack2(fmaxf(v2.z, 0.f), fmaxf(v2.w, 0.f));
            o1.z = pack2(fmaxf(v3.x, 0.f), fmaxf(v3.y, 0.f));
            o1.w = pack2(fmaxf(v3.z, 0.f), fmaxf(v3.w, 0.f));
            uint4* dst = (uint4*)(ybf + grow * HCH + h * 16);
            dst[0] = o0; dst[1] = o1;
        } else {
            const uint4* rb = (const uint4*)(residb + grow * HCH + h * 16);
            uint4 r0 = rb[0], r1 = rb[1];
            float4 o;
            float* op = outf + grow * HCH + h * 16;
            o.x = v0.x + bf2f((u16)(r0.x & 0xFFFF));
            o.y = v0.y + bf2f((u16)(r0.x >> 16));
            o.z = v0.z + bf2f((u16)(r0.y & 0xFFFF));
            o.w = v0.w + bf2f((u16)(r0.y >> 16));
            *(float4*)(op + 0) = o;
            o.x = v1.x + bf2f((u16)(r0.z & 0xFFFF));
            o.y = v1.y + bf2f((u16)(r0.z >> 16));
            o.z = v1.z + bf2f((u16)(r0.w & 0xFFFF));
            o.w = v1.w + bf2f((u16)(r0.w >> 16));
            *(float4*)(op + 4) = o;
            o.x = v2.x + bf2f((u16)(r1.x & 0xFFFF));
            o.y = v2.y + bf2f((u16)(r1.x >> 16));
            o.z = v2.z + bf2f((u16)(r1.y & 0xFFFF));
            o.w = v2.w + bf2f((u16)(r1.y >> 16));
            *(float4*)(op + 8) = o;
            o.x = v3.x + bf2f((u16)(r1.z & 0xFFFF));
            o.y = v3.y + bf2f((u16)(r1.z >> 16));
            o.z = v3.z + bf2f((u16)(r1.w & 0xFFFF));
            o.w = v3.w + bf2f((u16)(r1.w >> 16));
            *(float4*)(op + 12) = o;
        }
    }
}

// ---------------------------------------------------------------- launch ----
extern "C" void kernel_launch(void* const* d_in, const int* in_sizes, int n_in,
                              void* d_out, int out_size, void* d_ws, size_t ws_size,
                              hipStream_t stream) {
    const float* x   = (const float*)d_in[0];
    const float* Wa  = (const float*)d_in[1];
    const float* Wb  = (const float*)d_in[2];
    const int*   nbr = (const int*)d_in[3];
    float* out = (float*)d_out;

    char* ws = (char*)d_ws;
    const size_t xb_bytes = (size_t)(N_ROWS + 1) * HCH * sizeof(u16); // 33,554,560
    const size_t w_bytes  = (size_t)KOFF * HCH * HCH * sizeof(u16);   //    221,184
    u16* xb  = (u16*)ws;
    u16* yb  = (u16*)(ws + xb_bytes);
    u16* Wta = (u16*)(ws + 2 * xb_bytes);
    u16* Wtb = (u16*)(ws + 2 * xb_bytes + w_bytes);
    int* nbrT = (int*)(ws + 2 * xb_bytes + 2 * w_bytes);

    prep_all<<<17249, 256, 0, stream>>>(x, xb, yb, Wa, Wb, Wta, Wtb, nbr, nbrT);
    conv_kernel<true ><<<N_ROWS / 256, 256, 0, stream>>>(xb, Wta, nbrT, yb, nullptr, nullptr);
    conv_kernel<false><<<N_ROWS / 256, 256, 0, stream>>>(yb, Wtb, nbrT, nullptr, out, xb);
}